// Round 16
// baseline (209.182 us; speedup 1.0000x reference)
//
#include <hip/hip_runtime.h>
#include <stdint.h>

#define HDIM 1024
#define NEXP 32
#define IDIM 512
#define TOPK 6
#define NTOK 2048
#define NPAIR (NTOK*TOPK)   // 12288

typedef __attribute__((ext_vector_type(4))) float f32x4;
typedef __attribute__((ext_vector_type(8))) short s16x8;
typedef __attribute__((ext_vector_type(8))) __bf16 bf16x8;

static __device__ __forceinline__ f32x4 mfma16(s16x8 a, s16x8 b, f32x4 c){
  return __builtin_amdgcn_mfma_f32_16x16x32_bf16(
      __builtin_bit_cast(bf16x8, a), __builtin_bit_cast(bf16x8, b), c, 0, 0, 0);
}

static __device__ __forceinline__ short bf1(float f){
  return __builtin_bit_cast(short, (__bf16)f);
}
static __device__ __forceinline__ s16x8 pack8v(f32x4 a, f32x4 b){
  bf16x8 o;
  o[0]=(__bf16)a[0]; o[1]=(__bf16)a[1]; o[2]=(__bf16)a[2]; o[3]=(__bf16)a[3];
  o[4]=(__bf16)b[0]; o[5]=(__bf16)b[1]; o[6]=(__bf16)b[2]; o[7]=(__bf16)b[3];
  return __builtin_bit_cast(s16x8, o);
}

#define GLL16(SRC, DST) __builtin_amdgcn_global_load_lds( \
    (const __attribute__((address_space(1))) void*)(SRC), \
    (__attribute__((address_space(3))) void*)(DST), 16, 0, 0)

// counted waitcnt + scheduling fence (rule 18)
static __device__ __forceinline__ void wait_vm8(){
  asm volatile("s_waitcnt vmcnt(8)" ::: "memory");
  __builtin_amdgcn_sched_barrier(0);
}
static __device__ __forceinline__ void wait_vm0(){
  asm volatile("s_waitcnt vmcnt(0)" ::: "memory");
  __builtin_amdgcn_sched_barrier(0);
}
static __device__ __forceinline__ void barrier_raw(){
  __builtin_amdgcn_sched_barrier(0);
  __builtin_amdgcn_s_barrier();
  __builtin_amdgcn_sched_barrier(0);
}

// fragment read: lane holds 8 consecutive k of row (lane&15), k-chunk (lane>>4)*8
// XOR-swizzled read; staging pre-swizzles the global source column (rule 21).
static __device__ __forceinline__ s16x8 frag_ld(const short* lds, int row, int ks, int lane){
  int kb  = ks*64 + ((lane >> 4) << 4);
  int off = row*128 + (kb ^ ((row & 7) << 4));
  return *(const s16x8*)(lds + (off >> 1));
}

// 64KB-fp32 slab convert (2048 chunks of 8 floats), loads-first, cached stores
static __device__ __forceinline__ void conv_slab(const float* __restrict__ src,
                                                 short* __restrict__ dst, long cb, int tid){
  const f32x4* s4 = (const f32x4*)src;
  long i0 = cb*2048 + tid;
  f32x4 la[8], lc[8];
  #pragma unroll
  for (int it = 0; it < 8; ++it){
    long i = i0 + (long)it*256;
    la[it] = __builtin_nontemporal_load(s4 + 2*i);
    lc[it] = __builtin_nontemporal_load(s4 + 2*i + 1);
  }
  #pragma unroll
  for (int it = 0; it < 8; ++it){
    long i = i0 + (long)it*256;
    *(s16x8*)(dst + 8*i) = pack8v(la[it], lc[it]);
  }
}

// NT-store variant: stream bypasses L2/L3 in BOTH directions so co-resident
// GEMM weight panels are not evicted (R14 lesson: cached interleave => FETCH
// 126->233MB). Used only for the wdn->bdn stream inside k_gu.
static __device__ __forceinline__ void conv_slab_nt(const float* __restrict__ src,
                                                    short* __restrict__ dst, long cb, int tid){
  const f32x4* s4 = (const f32x4*)src;
  long i0 = cb*2048 + tid;
  f32x4 la[8], lc[8];
  #pragma unroll
  for (int it = 0; it < 8; ++it){
    long i = i0 + (long)it*256;
    la[it] = __builtin_nontemporal_load(s4 + 2*i);
    lc[it] = __builtin_nontemporal_load(s4 + 2*i + 1);
  }
  #pragma unroll
  for (int it = 0; it < 8; ++it){
    long i = i0 + (long)it*256;
    __builtin_nontemporal_store(pack8v(la[it], lc[it]), (s16x8*)(dst + 8*i));
  }
}

// ------ fused: router (blocks 0..511, 4 tok/block, counts zero at b==0) ----
// ------        + gu-side weight convert (blocks 512..2751): bgu/bsg/bsu/bsd
__global__ __launch_bounds__(256) void k_convert_router(const float* __restrict__ gu,
    const float* __restrict__ sg, const float* __restrict__ su,
    const float* __restrict__ sd,
    short* __restrict__ bgu, short* __restrict__ bsg,
    short* __restrict__ bsu, short* __restrict__ bsd,
    const float* __restrict__ x, const float* __restrict__ rw,
    const float* __restrict__ bias, short* __restrict__ xb,
    int* __restrict__ tki, float* __restrict__ tkw, int* __restrict__ counts){
  int b = blockIdx.x;
  if (b >= 512){
    int cb = b - 512;
    if (cb < 2048)      conv_slab(gu, bgu, cb, threadIdx.x);
    else if (cb < 2112) conv_slab(sg, bsg, cb - 2048, threadIdx.x);
    else if (cb < 2176) conv_slab(su, bsu, cb - 2112, threadIdx.x);
    else                conv_slab(sd, bsd, cb - 2176, threadIdx.x);
    return;
  }
  // ---- router path: 1 token/wave, fp32 dot, no global atomics ----
  if (b == 0 && threadIdx.x < NEXP) counts[threadIdx.x] = 0;  // hist runs next kernel
  int wid = threadIdx.x >> 6, lane = threadIdx.x & 63;
  int t = b*4 + wid;
  const f32x4* xr4 = (const f32x4*)(x + (long)t*HDIM);
  f32x4 xv[4];
  #pragma unroll
  for (int j = 0; j < 4; ++j) xv[j] = xr4[lane + j*64];
  #pragma unroll
  for (int j = 0; j < 4; ++j){
    short4 o; o.x = bf1(xv[j][0]); o.y = bf1(xv[j][1]); o.z = bf1(xv[j][2]); o.w = bf1(xv[j][3]);
    *(short4*)(xb + (long)t*HDIM + (lane + j*64)*4) = o;
  }
  float mylogit = -1e30f;
  #pragma unroll 8
  for (int e = 0; e < NEXP; ++e){
    const f32x4* wr4 = (const f32x4*)(rw + (long)e*HDIM);
    f32x4 acc = xv[0]*wr4[lane];
    acc += xv[1]*wr4[lane + 64];
    acc += xv[2]*wr4[lane + 128];
    acc += xv[3]*wr4[lane + 192];
    float s = acc[0] + acc[1] + acc[2] + acc[3];
    #pragma unroll
    for (int sh = 32; sh; sh >>= 1) s += __shfl_xor(s, sh);
    if (lane == e) mylogit = s;
  }
  float m = mylogit;
  #pragma unroll
  for (int sh = 32; sh; sh >>= 1) m = fmaxf(m, __shfl_xor(m, sh));
  float p = (lane < NEXP) ? __expf(mylogit - m) : 0.f;
  float sum = p;
  #pragma unroll
  for (int sh = 32; sh; sh >>= 1) sum += __shfl_xor(sum, sh);
  p = p / sum;
  float rem = (lane < NEXP) ? (p + bias[lane]) : -1e30f;
  int myidx = 0; float myw = 0.f;
  for (int k = 0; k < TOPK; ++k){
    float vv = rem; int ix = lane;
    #pragma unroll
    for (int sh = 32; sh; sh >>= 1){
      float ov = __shfl_xor(vv, sh); int oi = __shfl_xor(ix, sh);
      if (ov > vv || (ov == vv && oi < ix)){ vv = ov; ix = oi; }
    }
    float pw = __shfl(p, ix);
    if (lane == ix) rem = -1e30f;
    if (lane == k){ myidx = ix; myw = pw; }
  }
  float s6 = (lane < TOPK) ? myw : 0.f;
  #pragma unroll
  for (int sh = 32; sh; sh >>= 1) s6 += __shfl_xor(s6, sh);
  if (lane < TOPK){
    tki[t*TOPK + lane] = myidx;
    tkw[t*TOPK + lane] = myw / fmaxf(s6, 1e-12f);
  }
}

// ---------------- histogram: LDS-aggregated, 32 global atomics per block ---
__global__ __launch_bounds__(256) void k_hist(const int* __restrict__ tki,
                                              int* __restrict__ counts){
  __shared__ int h[NEXP];
  int tid = threadIdx.x;
  if (tid < NEXP) h[tid] = 0;
  __syncthreads();
  #pragma unroll
  for (int j = 0; j < 4; ++j)
    atomicAdd(&h[tki[blockIdx.x*1024 + j*256 + tid]], 1);
  __syncthreads();
  if (tid < NEXP) atomicAdd(&counts[tid], h[tid]);
}

__global__ void k_scan(const int* __restrict__ counts, int* __restrict__ offsets,
                       int* __restrict__ cursor){
  if (threadIdx.x == 0){
    int s = 0;
    for (int e = 0; e < NEXP; ++e){ offsets[e] = s; cursor[e] = s; s += counts[e]; }
    offsets[NEXP] = s;
  }
}

// ---------------- scatter: LDS local ranks, 32 global atomics per block ----
__global__ __launch_bounds__(256) void k_scatter(const int* __restrict__ tki,
    const float* __restrict__ tkw, int* __restrict__ cursor,
    int* __restrict__ permt, float* __restrict__ permw, int* __restrict__ pairpos){
  __shared__ int lcnt[NEXP], lbase[NEXP];
  int tid = threadIdx.x;
  if (tid < NEXP) lcnt[tid] = 0;
  __syncthreads();
  int e[4], lr[4];
  #pragma unroll
  for (int j = 0; j < 4; ++j){
    int i = blockIdx.x*1024 + j*256 + tid;
    e[j] = tki[i];
    lr[j] = atomicAdd(&lcnt[e[j]], 1);
  }
  __syncthreads();
  if (tid < NEXP) lbase[tid] = atomicAdd(&cursor[tid], lcnt[tid]);
  __syncthreads();
  #pragma unroll
  for (int j = 0; j < 4; ++j){
    int i = blockIdx.x*1024 + j*256 + tid;
    int pos = lbase[e[j]] + lr[j];
    permt[pos] = i / TOPK;
    permw[pos] = tkw[i];
    pairpos[i] = pos;
  }
}

// ---------------- gate+up + INTERLEAVED NT bdn convert ----------------------
// grid (10, 16, NEXP+2): x<8 = GEMM n-tile; x in {8,9} = bdn-convert slab
// cb = 2*(y+16*z)+(x-8), guard cb<1024. Convert blocks co-reside with GEMM
// blocks (BW-slack overlap); the NT load+store stream does not allocate in
// L2/L3, so weight panels stay resident (fixes R14's FETCH 126->233MB thrash).
// z<2: shared (n0 = z*512 + x*64); z>=2: expert e = z-2.
__global__ __launch_bounds__(256,2) void k_gu(const short* __restrict__ xb,
    const short* __restrict__ bgu, const short* __restrict__ bsg,
    const short* __restrict__ bsu, const int* __restrict__ offsets,
    const int* __restrict__ permt, short* __restrict__ hmid, short* __restrict__ sb,
    const float* __restrict__ wdnf, short* __restrict__ bdn){
  int zz = blockIdx.z;
  int tid = threadIdx.x;
  if (blockIdx.x >= 8){
    long cb = 2L*(blockIdx.y + 16L*zz) + (blockIdx.x - 8);
    if (cb < 1024) conv_slab_nt(wdnf, bdn, cb, tid);
    return;
  }
  bool expert = (zz >= 2);
  int lane = tid & 63, wid = tid >> 6, wr = wid >> 1, wc = wid & 1;
  __shared__ short As[2][128*64];
  __shared__ short Bg[2][64*64];
  __shared__ short Bu[2][64*64];
  __shared__ int rowmap[128];
  int m0 = blockIdx.y*128, n0;
  int off = 0, seg = NTOK;
  const short *wg, *wu;
  if (expert){
    int e = zz - 2;
    off = offsets[e]; seg = offsets[e+1] - off;
    if (m0 >= seg) return;
    n0 = blockIdx.x*64;
    wg = bgu + (long)e*1024*HDIM + (long)n0*HDIM;
    wu = wg + (long)IDIM*HDIM;
    if (tid < 128) rowmap[tid] = permt[off + min(m0 + tid, seg - 1)];
  } else {
    n0 = zz*512 + blockIdx.x*64;
    wg = bsg + (long)n0*HDIM;
    wu = bsu + (long)n0*HDIM;
    if (tid < 128) rowmap[tid] = m0 + tid;
  }
  __syncthreads();   // rowmap visible
  const short* aS[4]; int aD[4];
  #pragma unroll
  for (int p = 0; p < 4; ++p){
    int c = p*256 + tid, row = c >> 3;
    int skb = ((c & 7) << 4) ^ ((row & 7) << 4);
    aS[p] = xb + (long)rowmap[row]*HDIM + (skb >> 1);
    aD[p] = c*8;
  }
  const short *gS[2], *uS[2]; int bD[2];
  #pragma unroll
  for (int p = 0; p < 2; ++p){
    int c = p*256 + tid, row = c >> 3;
    int skb = ((c & 7) << 4) ^ ((row & 7) << 4);
    gS[p] = wg + (long)row*HDIM + (skb >> 1);
    uS[p] = wu + (long)row*HDIM + (skb >> 1);
    bD[p] = c*8;
  }
  auto ISSUE = [&](int kt_, int buf){
    int k0 = kt_*64;
    #pragma unroll
    for (int p = 0; p < 4; ++p) GLL16(aS[p]+k0, &As[buf][aD[p]]);
    #pragma unroll
    for (int p = 0; p < 2; ++p){ GLL16(gS[p]+k0, &Bg[buf][bD[p]]); GLL16(uS[p]+k0, &Bu[buf][bD[p]]); }
  };
  f32x4 z = {0.f,0.f,0.f,0.f};
  f32x4 ag[4][2], au[4][2];
  for (int i=0;i<4;i++) for (int j=0;j<2;j++){ ag[i][j]=z; au[i][j]=z; }
  const int nkt = HDIM/64;
  ISSUE(0, 0);
  ISSUE(1, 1);          // 16 in flight
  wait_vm8();           // tile0 landed
  barrier_raw();
  int cur = 0;
  for (int kt = 0; kt < nkt; ++kt){
    #pragma unroll
    for (int ks = 0; ks < 2; ++ks){
      s16x8 af[4], g2[2], u2[2];
      #pragma unroll
      for (int i = 0; i < 4; ++i) af[i] = frag_ld(&As[cur][0], wr*64 + i*16 + (lane&15), ks, lane);
      #pragma unroll
      for (int j = 0; j < 2; ++j){
        g2[j] = frag_ld(&Bg[cur][0], wc*32 + j*16 + (lane&15), ks, lane);
        u2[j] = frag_ld(&Bu[cur][0], wc*32 + j*16 + (lane&15), ks, lane);
      }
      #pragma unroll
      for (int i = 0; i < 4; ++i)
        #pragma unroll
        for (int j = 0; j < 2; ++j){
          ag[i][j] = mfma16(af[i], g2[j], ag[i][j]);
          au[i][j] = mfma16(af[i], u2[j], au[i][j]);
        }
    }
    barrier_raw();                        // all waves done reading buf[cur]
    if (kt + 2 < nkt){
      ISSUE(kt + 2, cur);                 // refill freed buffer; 16 in flight
      wait_vm8();                         // t+1 landed, t+2 stays in flight
      barrier_raw();
    } else if (kt + 1 < nkt){
      wait_vm0();                         // only t+1 outstanding
      barrier_raw();
    }
    cur ^= 1;
  }
  #pragma unroll
  for (int i = 0; i < 4; ++i){
    int mrow = wr*64 + i*16 + ((lane >> 4) << 2);
    #pragma unroll
    for (int j = 0; j < 2; ++j){
      int col = n0 + wc*32 + j*16 + (lane & 15);
      #pragma unroll
      for (int r = 0; r < 4; ++r){
        int m = mrow + r;
        float gv = ag[i][j][r], uv = au[i][j][r];
        float sv = gv / (1.f + __expf(-gv)) * uv;
        if (expert){
          if (m0 + m < seg)
            hmid[(long)(off + m0 + m)*IDIM + col] = bf1(sv);
        } else {
          sb[(long)(m0 + m)*1024 + col] = bf1(sv);
        }
      }
    }
  }
}

// ---------------- down, counted-vmcnt 2-buf pipeline (shared z==0 first) ---
// (R9-proven config)
__global__ __launch_bounds__(256,2) void k_down(const short* __restrict__ hmid,
    const short* __restrict__ bdn, const short* __restrict__ sb,
    const short* __restrict__ bsd, const int* __restrict__ offsets,
    const int* __restrict__ permt, const float* __restrict__ permw,
    short* __restrict__ y, float* __restrict__ out){
  bool expert = (blockIdx.z >= 1);
  int tid = threadIdx.x, lane = tid & 63, wid = tid >> 6, wr = wid >> 1, wc = wid & 1;
  __shared__ short As[2][128*64];
  __shared__ short Bs[2][128*64];
  __shared__ int rowmap[128];
  int m0 = blockIdx.y*128, n0 = blockIdx.x*128;
  int off = 0, seg = NTOK, nkt, lda, ldb;
  const short* Ag; const short* Bgp;
  if (expert){
    int e = blockIdx.z - 1;
    off = offsets[e]; seg = offsets[e+1] - off;
    if (m0 >= seg) return;
    Ag = hmid; lda = IDIM;
    Bgp = bdn + (long)e*HDIM*IDIM + (long)n0*IDIM; ldb = IDIM;
    nkt = IDIM/64;
    if (tid < 128) rowmap[tid] = off + min(m0 + tid, seg - 1);
  } else {
    Ag = sb; lda = 1024;
    Bgp = bsd + (long)n0*1024; ldb = 1024;
    nkt = 1024/64;
    if (tid < 128) rowmap[tid] = m0 + tid;
  }
  __syncthreads();
  const short *aS[4], *bS[4]; int cD[4];
  #pragma unroll
  for (int p = 0; p < 4; ++p){
    int c = p*256 + tid, row = c >> 3;
    int skb = ((c & 7) << 4) ^ ((row & 7) << 4);
    aS[p] = Ag + (long)rowmap[row]*lda + (skb >> 1);
    bS[p] = Bgp + (long)row*ldb + (skb >> 1);
    cD[p] = c*8;
  }
  auto ISSUE = [&](int kt_, int buf){
    int k0 = kt_*64;
    #pragma unroll
    for (int p = 0; p < 4; ++p){ GLL16(aS[p]+k0, &As[buf][cD[p]]); GLL16(bS[p]+k0, &Bs[buf][cD[p]]); }
  };
  f32x4 z = {0.f,0.f,0.f,0.f};
  f32x4 acc[4][4];
  for (int i=0;i<4;i++) for (int j=0;j<4;j++) acc[i][j]=z;
  ISSUE(0, 0);
  ISSUE(1, 1);
  wait_vm8();
  barrier_raw();
  int cur = 0;
  for (int kt = 0; kt < nkt; ++kt){
    #pragma unroll
    for (int ks = 0; ks < 2; ++ks){
      s16x8 af[4], bf[4];
      #pragma unroll
      for (int i = 0; i < 4; ++i){
        af[i] = frag_ld(&As[cur][0], wr*64 + i*16 + (lane&15), ks, lane);
        bf[i] = frag_ld(&Bs[cur][0], wc*64 + i*16 + (lane&15), ks, lane);
      }
      #pragma unroll
      for (int i = 0; i < 4; ++i)
        #pragma unroll
        for (int j = 0; j < 4; ++j)
          acc[i][j] = mfma16(af[i], bf[j], acc[i][j]);
    }
    barrier_raw();
    if (kt + 2 < nkt){
      ISSUE(kt + 2, cur);
      wait_vm8();
      barrier_raw();
    } else if (kt + 1 < nkt){
      wait_vm0();
      barrier_raw();
    }
    cur ^= 1;
  }
  if (expert){
    #pragma unroll
    for (int i = 0; i < 4; ++i){
      int mrow = wr*64 + i*16 + ((lane >> 4) << 2);
      #pragma unroll
      for (int r = 0; r < 4; ++r){
        int m = mrow + r;
        if (m0 + m < seg){
          int p = off + m0 + m;
          float w = permw[p];
          #pragma unroll
          for (int j = 0; j < 4; ++j){
            int col = n0 + wc*64 + j*16 + (lane & 15);
            y[(long)p*HDIM + col] = bf1(w*acc[i][j][r]);
          }
        }
      }
    }
  } else {
    #pragma unroll
    for (int i = 0; i < 4; ++i){
      int mrow = m0 + wr*64 + i*16 + ((lane >> 4) << 2);
      #pragma unroll
      for (int j = 0; j < 4; ++j){
        int col = n0 + wc*64 + j*16 + (lane & 15);
        #pragma unroll
        for (int r = 0; r < 4; ++r)
          out[(long)(mrow + r)*HDIM + col] = acc[i][j][r];
      }
    }
  }
}

// ---------------- finalize: out[t] += sum_k bf16 y[pairpos[t,k]] -----------
__global__ __launch_bounds__(256) void k_finalize(const short* __restrict__ y,
    const int* __restrict__ pairpos, float* __restrict__ out){
  int t = blockIdx.x, tid = threadIdx.x;
  const int* pp = pairpos + t*TOPK;
  float4* o4 = (float4*)(out + (long)t*HDIM);
  float4 acc = o4[tid];
  #pragma unroll
  for (int k = 0; k < TOPK; ++k){
    const short4 v = *(const short4*)(y + (long)pp[k]*HDIM + tid*4);
    acc.x += (float)__builtin_bit_cast(__bf16, v.x);
    acc.y += (float)__builtin_bit_cast(__bf16, v.y);
    acc.z += (float)__builtin_bit_cast(__bf16, v.z);
    acc.w += (float)__builtin_bit_cast(__bf16, v.w);
  }
  o4[tid] = acc;
}

extern "C" void kernel_launch(void* const* d_in, const int* in_sizes, int n_in,
                              void* d_out, int out_size, void* d_ws, size_t ws_size,
                              hipStream_t stream){
  const float* x    = (const float*)d_in[0];
  const float* rw   = (const float*)d_in[1];
  const float* bias = (const float*)d_in[2];
  const float* wgu  = (const float*)d_in[3];
  const float* wdn  = (const float*)d_in[4];
  const float* wsg  = (const float*)d_in[5];
  const float* wsu  = (const float*)d_in[6];
  const float* wsd  = (const float*)d_in[7];
  float* out = (float*)d_out;

  char* ws = (char*)d_ws;
  size_t o = 0;
  auto alloc = [&](size_t bytes){ void* p = ws + o; o += (bytes + 255) & ~(size_t)255; return p; };
  short* bgu  = (short*)alloc(67108864);   // [E,2I,H] bf16; dead after k_gu
  short* bdn  = (short*)alloc(33554432);   // [E,H,I]  bf16 (NT-written inside k_gu)
  short* bsg  = (short*)alloc(2097152);
  short* bsu  = (short*)alloc(2097152);
  short* bsd  = (short*)alloc(2097152);
  short* xb   = (short*)alloc(4194304);    // [T,H] bf16
  short* sb   = (short*)alloc(4194304);    // [T,IS] bf16
  short* hmid = (short*)alloc(12582912);   // [P,I] bf16
  int*   tki  = (int*)alloc(NPAIR*4);
  float* tkw  = (float*)alloc(NPAIR*4);
  int*   counts  = (int*)alloc(256);
  int*   offsets = (int*)alloc(256);
  int*   cursor  = (int*)alloc(256);
  int*   permt   = (int*)alloc(NPAIR*4);
  float* permw   = (float*)alloc(NPAIR*4);
  int*   pairpos = (int*)alloc(NPAIR*4);
  short* y = (short*)bgu;                  // alias: y [NPAIR,H] bf16 (25MB) over dead bgu
  (void)ws_size; (void)in_sizes; (void)n_in; (void)out_size;

  k_convert_router<<<dim3(512 + 2240), dim3(256), 0, stream>>>(
      wgu, wsg, wsu, wsd, bgu, bsg, bsu, bsd,
      x, rw, bias, xb, tki, tkw, counts);
  k_hist<<<dim3(NPAIR/1024), dim3(256), 0, stream>>>(tki, counts);
  k_scan<<<dim3(1), dim3(64), 0, stream>>>(counts, offsets, cursor);
  k_scatter<<<dim3(NPAIR/1024), dim3(256), 0, stream>>>(tki, tkw, cursor, permt, permw, pairpos);
  k_gu<<<dim3(10, 16, NEXP+2), dim3(256), 0, stream>>>(xb, bgu, bsg, bsu, offsets, permt,
                                                       hmid, sb, wdn, bdn);
  k_down<<<dim3(8, 16, NEXP+1), dim3(256), 0, stream>>>(hmid, bdn, sb, bsd, offsets, permt, permw, y, out);
  k_finalize<<<dim3(NTOK), dim3(256), 0, stream>>>(y, pairpos, out);
}

// Round 17
// 181.726 us; speedup vs baseline: 1.1511x; 1.1511x over previous
//
#include <hip/hip_runtime.h>
#include <stdint.h>

#define HDIM 1024
#define NEXP 32
#define IDIM 512
#define TOPK 6
#define NTOK 2048
#define NPAIR (NTOK*TOPK)   // 12288

typedef __attribute__((ext_vector_type(4))) float f32x4;
typedef __attribute__((ext_vector_type(8))) short s16x8;
typedef __attribute__((ext_vector_type(8))) __bf16 bf16x8;

static __device__ __forceinline__ f32x4 mfma16(s16x8 a, s16x8 b, f32x4 c){
  return __builtin_amdgcn_mfma_f32_16x16x32_bf16(
      __builtin_bit_cast(bf16x8, a), __builtin_bit_cast(bf16x8, b), c, 0, 0, 0);
}

static __device__ __forceinline__ short bf1(float f){
  return __builtin_bit_cast(short, (__bf16)f);
}
static __device__ __forceinline__ s16x8 pack8v(f32x4 a, f32x4 b){
  bf16x8 o;
  o[0]=(__bf16)a[0]; o[1]=(__bf16)a[1]; o[2]=(__bf16)a[2]; o[3]=(__bf16)a[3];
  o[4]=(__bf16)b[0]; o[5]=(__bf16)b[1]; o[6]=(__bf16)b[2]; o[7]=(__bf16)b[3];
  return __builtin_bit_cast(s16x8, o);
}

#define GLL16(SRC, DST) __builtin_amdgcn_global_load_lds( \
    (const __attribute__((address_space(1))) void*)(SRC), \
    (__attribute__((address_space(3))) void*)(DST), 16, 0, 0)

// counted waitcnt + scheduling fence (rule 18)
static __device__ __forceinline__ void wait_vm8(){
  asm volatile("s_waitcnt vmcnt(8)" ::: "memory");
  __builtin_amdgcn_sched_barrier(0);
}
static __device__ __forceinline__ void wait_vm0(){
  asm volatile("s_waitcnt vmcnt(0)" ::: "memory");
  __builtin_amdgcn_sched_barrier(0);
}
static __device__ __forceinline__ void barrier_raw(){
  __builtin_amdgcn_sched_barrier(0);
  __builtin_amdgcn_s_barrier();
  __builtin_amdgcn_sched_barrier(0);
}

// fragment read: lane holds 8 consecutive k of row (lane&15), k-chunk (lane>>4)*8
// XOR-swizzled read; staging pre-swizzles the global source column (rule 21).
static __device__ __forceinline__ s16x8 frag_ld(const short* lds, int row, int ks, int lane){
  int kb  = ks*64 + ((lane >> 4) << 4);
  int off = row*128 + (kb ^ ((row & 7) << 4));
  return *(const s16x8*)(lds + (off >> 1));
}

// 64KB-fp32 slab convert (2048 chunks of 8 floats), loads-first
static __device__ __forceinline__ void conv_slab(const float* __restrict__ src,
                                                 short* __restrict__ dst, long cb, int tid){
  const f32x4* s4 = (const f32x4*)src;
  long i0 = cb*2048 + tid;
  f32x4 la[8], lc[8];
  #pragma unroll
  for (int it = 0; it < 8; ++it){
    long i = i0 + (long)it*256;
    la[it] = __builtin_nontemporal_load(s4 + 2*i);
    lc[it] = __builtin_nontemporal_load(s4 + 2*i + 1);
  }
  #pragma unroll
  for (int it = 0; it < 8; ++it){
    long i = i0 + (long)it*256;
    *(s16x8*)(dst + 8*i) = pack8v(la[it], lc[it]);
  }
}

// ------ fused: router (blocks 0..511, 4 tok/block, counts zero at b==0) ----
// ------        + gu-side weight convert (blocks 512..2751): bgu/bsg/bsu/bsd
__global__ __launch_bounds__(256) void k_convert_router(const float* __restrict__ gu,
    const float* __restrict__ sg, const float* __restrict__ su,
    const float* __restrict__ sd,
    short* __restrict__ bgu, short* __restrict__ bsg,
    short* __restrict__ bsu, short* __restrict__ bsd,
    const float* __restrict__ x, const float* __restrict__ rw,
    const float* __restrict__ bias, short* __restrict__ xb,
    int* __restrict__ tki, float* __restrict__ tkw, int* __restrict__ counts){
  int b = blockIdx.x;
  if (b >= 512){
    int cb = b - 512;
    if (cb < 2048)      conv_slab(gu, bgu, cb, threadIdx.x);
    else if (cb < 2112) conv_slab(sg, bsg, cb - 2048, threadIdx.x);
    else if (cb < 2176) conv_slab(su, bsu, cb - 2112, threadIdx.x);
    else                conv_slab(sd, bsd, cb - 2176, threadIdx.x);
    return;
  }
  // ---- router path: 1 token/wave, fp32 dot, no global atomics ----
  if (b == 0 && threadIdx.x < NEXP) counts[threadIdx.x] = 0;  // hist runs next kernel
  int wid = threadIdx.x >> 6, lane = threadIdx.x & 63;
  int t = b*4 + wid;
  const f32x4* xr4 = (const f32x4*)(x + (long)t*HDIM);
  f32x4 xv[4];
  #pragma unroll
  for (int j = 0; j < 4; ++j) xv[j] = xr4[lane + j*64];
  #pragma unroll
  for (int j = 0; j < 4; ++j){
    short4 o; o.x = bf1(xv[j][0]); o.y = bf1(xv[j][1]); o.z = bf1(xv[j][2]); o.w = bf1(xv[j][3]);
    *(short4*)(xb + (long)t*HDIM + (lane + j*64)*4) = o;
  }
  float mylogit = -1e30f;
  #pragma unroll 8
  for (int e = 0; e < NEXP; ++e){
    const f32x4* wr4 = (const f32x4*)(rw + (long)e*HDIM);
    f32x4 acc = xv[0]*wr4[lane];
    acc += xv[1]*wr4[lane + 64];
    acc += xv[2]*wr4[lane + 128];
    acc += xv[3]*wr4[lane + 192];
    float s = acc[0] + acc[1] + acc[2] + acc[3];
    #pragma unroll
    for (int sh = 32; sh; sh >>= 1) s += __shfl_xor(s, sh);
    if (lane == e) mylogit = s;
  }
  float m = mylogit;
  #pragma unroll
  for (int sh = 32; sh; sh >>= 1) m = fmaxf(m, __shfl_xor(m, sh));
  float p = (lane < NEXP) ? __expf(mylogit - m) : 0.f;
  float sum = p;
  #pragma unroll
  for (int sh = 32; sh; sh >>= 1) sum += __shfl_xor(sum, sh);
  p = p / sum;
  float rem = (lane < NEXP) ? (p + bias[lane]) : -1e30f;
  int myidx = 0; float myw = 0.f;
  for (int k = 0; k < TOPK; ++k){
    float vv = rem; int ix = lane;
    #pragma unroll
    for (int sh = 32; sh; sh >>= 1){
      float ov = __shfl_xor(vv, sh); int oi = __shfl_xor(ix, sh);
      if (ov > vv || (ov == vv && oi < ix)){ vv = ov; ix = oi; }
    }
    float pw = __shfl(p, ix);
    if (lane == ix) rem = -1e30f;
    if (lane == k){ myidx = ix; myw = pw; }
  }
  float s6 = (lane < TOPK) ? myw : 0.f;
  #pragma unroll
  for (int sh = 32; sh; sh >>= 1) s6 += __shfl_xor(s6, sh);
  if (lane < TOPK){
    tki[t*TOPK + lane] = myidx;
    tkw[t*TOPK + lane] = myw / fmaxf(s6, 1e-12f);
  }
}

// ---------------- histogram: LDS-aggregated, 32 global atomics per block ---
__global__ __launch_bounds__(256) void k_hist(const int* __restrict__ tki,
                                              int* __restrict__ counts){
  __shared__ int h[NEXP];
  int tid = threadIdx.x;
  if (tid < NEXP) h[tid] = 0;
  __syncthreads();
  #pragma unroll
  for (int j = 0; j < 4; ++j)
    atomicAdd(&h[tki[blockIdx.x*1024 + j*256 + tid]], 1);
  __syncthreads();
  if (tid < NEXP) atomicAdd(&counts[tid], h[tid]);
}

__global__ void k_scan(const int* __restrict__ counts, int* __restrict__ offsets,
                       int* __restrict__ cursor){
  if (threadIdx.x == 0){
    int s = 0;
    for (int e = 0; e < NEXP; ++e){ offsets[e] = s; cursor[e] = s; s += counts[e]; }
    offsets[NEXP] = s;
  }
}

// ---------------- scatter: LDS local ranks, 32 global atomics per block ----
__global__ __launch_bounds__(256) void k_scatter(const int* __restrict__ tki,
    const float* __restrict__ tkw, int* __restrict__ cursor,
    int* __restrict__ permt, float* __restrict__ permw, int* __restrict__ pairpos){
  __shared__ int lcnt[NEXP], lbase[NEXP];
  int tid = threadIdx.x;
  if (tid < NEXP) lcnt[tid] = 0;
  __syncthreads();
  int e[4], lr[4];
  #pragma unroll
  for (int j = 0; j < 4; ++j){
    int i = blockIdx.x*1024 + j*256 + tid;
    e[j] = tki[i];
    lr[j] = atomicAdd(&lcnt[e[j]], 1);
  }
  __syncthreads();
  if (tid < NEXP) lbase[tid] = atomicAdd(&cursor[tid], lcnt[tid]);
  __syncthreads();
  #pragma unroll
  for (int j = 0; j < 4; ++j){
    int i = blockIdx.x*1024 + j*256 + tid;
    int pos = lbase[e[j]] + lr[j];
    permt[pos] = i / TOPK;
    permw[pos] = tkw[i];
    pairpos[i] = pos;
  }
}

// ---------------- gate+up + TAIL bdn convert --------------------------------
// grid (8, 16, NEXP+10): z<2 shared (n0 = z*512 + x*64); z in [2,34) expert
// e = z-2; z >= 34 bdn-convert slab cb=(z-34)*128+y*8+x — dispatched LAST so
// the 96MB wdn stream backfills CUs as GEMM blocks drain. Measured placement
// taxonomy: head 183.2 / interleave 204 (FETCH 126->233MB panel thrash; NT
// stores don't fix it, R16: 209) / tail 182.9 (winner).
__global__ __launch_bounds__(256,2) void k_gu(const short* __restrict__ xb,
    const short* __restrict__ bgu, const short* __restrict__ bsg,
    const short* __restrict__ bsu, const int* __restrict__ offsets,
    const int* __restrict__ permt, short* __restrict__ hmid, short* __restrict__ sb,
    const float* __restrict__ wdnf, short* __restrict__ bdn){
  int zz = blockIdx.z;
  int tid = threadIdx.x;
  if (zz >= NEXP + 2){
    long cb = (long)(zz - (NEXP + 2))*128 + blockIdx.y*8 + blockIdx.x;
    conv_slab(wdnf, bdn, cb, tid);
    return;
  }
  bool expert = (zz >= 2);
  int lane = tid & 63, wid = tid >> 6, wr = wid >> 1, wc = wid & 1;
  __shared__ short As[2][128*64];
  __shared__ short Bg[2][64*64];
  __shared__ short Bu[2][64*64];
  __shared__ int rowmap[128];
  int m0 = blockIdx.y*128, n0;
  int off = 0, seg = NTOK;
  const short *wg, *wu;
  if (expert){
    int e = zz - 2;
    off = offsets[e]; seg = offsets[e+1] - off;
    if (m0 >= seg) return;
    n0 = blockIdx.x*64;
    wg = bgu + (long)e*1024*HDIM + (long)n0*HDIM;
    wu = wg + (long)IDIM*HDIM;
    if (tid < 128) rowmap[tid] = permt[off + min(m0 + tid, seg - 1)];
  } else {
    n0 = zz*512 + blockIdx.x*64;
    wg = bsg + (long)n0*HDIM;
    wu = bsu + (long)n0*HDIM;
    if (tid < 128) rowmap[tid] = m0 + tid;
  }
  __syncthreads();   // rowmap visible
  const short* aS[4]; int aD[4];
  #pragma unroll
  for (int p = 0; p < 4; ++p){
    int c = p*256 + tid, row = c >> 3;
    int skb = ((c & 7) << 4) ^ ((row & 7) << 4);
    aS[p] = xb + (long)rowmap[row]*HDIM + (skb >> 1);
    aD[p] = c*8;
  }
  const short *gS[2], *uS[2]; int bD[2];
  #pragma unroll
  for (int p = 0; p < 2; ++p){
    int c = p*256 + tid, row = c >> 3;
    int skb = ((c & 7) << 4) ^ ((row & 7) << 4);
    gS[p] = wg + (long)row*HDIM + (skb >> 1);
    uS[p] = wu + (long)row*HDIM + (skb >> 1);
    bD[p] = c*8;
  }
  auto ISSUE = [&](int kt_, int buf){
    int k0 = kt_*64;
    #pragma unroll
    for (int p = 0; p < 4; ++p) GLL16(aS[p]+k0, &As[buf][aD[p]]);
    #pragma unroll
    for (int p = 0; p < 2; ++p){ GLL16(gS[p]+k0, &Bg[buf][bD[p]]); GLL16(uS[p]+k0, &Bu[buf][bD[p]]); }
  };
  f32x4 z = {0.f,0.f,0.f,0.f};
  f32x4 ag[4][2], au[4][2];
  for (int i=0;i<4;i++) for (int j=0;j<2;j++){ ag[i][j]=z; au[i][j]=z; }
  const int nkt = HDIM/64;
  ISSUE(0, 0);
  ISSUE(1, 1);          // 16 in flight
  wait_vm8();           // tile0 landed
  barrier_raw();
  int cur = 0;
  for (int kt = 0; kt < nkt; ++kt){
    #pragma unroll
    for (int ks = 0; ks < 2; ++ks){
      s16x8 af[4], g2[2], u2[2];
      #pragma unroll
      for (int i = 0; i < 4; ++i) af[i] = frag_ld(&As[cur][0], wr*64 + i*16 + (lane&15), ks, lane);
      #pragma unroll
      for (int j = 0; j < 2; ++j){
        g2[j] = frag_ld(&Bg[cur][0], wc*32 + j*16 + (lane&15), ks, lane);
        u2[j] = frag_ld(&Bu[cur][0], wc*32 + j*16 + (lane&15), ks, lane);
      }
      #pragma unroll
      for (int i = 0; i < 4; ++i)
        #pragma unroll
        for (int j = 0; j < 2; ++j){
          ag[i][j] = mfma16(af[i], g2[j], ag[i][j]);
          au[i][j] = mfma16(af[i], u2[j], au[i][j]);
        }
    }
    barrier_raw();                        // all waves done reading buf[cur]
    if (kt + 2 < nkt){
      ISSUE(kt + 2, cur);                 // refill freed buffer; 16 in flight
      wait_vm8();                         // t+1 landed, t+2 stays in flight
      barrier_raw();
    } else if (kt + 1 < nkt){
      wait_vm0();                         // only t+1 outstanding
      barrier_raw();
    }
    cur ^= 1;
  }
  #pragma unroll
  for (int i = 0; i < 4; ++i){
    int mrow = wr*64 + i*16 + ((lane >> 4) << 2);
    #pragma unroll
    for (int j = 0; j < 2; ++j){
      int col = n0 + wc*32 + j*16 + (lane & 15);
      #pragma unroll
      for (int r = 0; r < 4; ++r){
        int m = mrow + r;
        float gv = ag[i][j][r], uv = au[i][j][r];
        float sv = gv / (1.f + __expf(-gv)) * uv;
        if (expert){
          if (m0 + m < seg)
            hmid[(long)(off + m0 + m)*IDIM + col] = bf1(sv);
        } else {
          sb[(long)(m0 + m)*1024 + col] = bf1(sv);
        }
      }
    }
  }
}

// ---------------- down, counted-vmcnt 2-buf pipeline (shared z==0 first) ---
// (R9-proven config)
__global__ __launch_bounds__(256,2) void k_down(const short* __restrict__ hmid,
    const short* __restrict__ bdn, const short* __restrict__ sb,
    const short* __restrict__ bsd, const int* __restrict__ offsets,
    const int* __restrict__ permt, const float* __restrict__ permw,
    short* __restrict__ y, float* __restrict__ out){
  bool expert = (blockIdx.z >= 1);
  int tid = threadIdx.x, lane = tid & 63, wid = tid >> 6, wr = wid >> 1, wc = wid & 1;
  __shared__ short As[2][128*64];
  __shared__ short Bs[2][128*64];
  __shared__ int rowmap[128];
  int m0 = blockIdx.y*128, n0 = blockIdx.x*128;
  int off = 0, seg = NTOK, nkt, lda, ldb;
  const short* Ag; const short* Bgp;
  if (expert){
    int e = blockIdx.z - 1;
    off = offsets[e]; seg = offsets[e+1] - off;
    if (m0 >= seg) return;
    Ag = hmid; lda = IDIM;
    Bgp = bdn + (long)e*HDIM*IDIM + (long)n0*IDIM; ldb = IDIM;
    nkt = IDIM/64;
    if (tid < 128) rowmap[tid] = off + min(m0 + tid, seg - 1);
  } else {
    Ag = sb; lda = 1024;
    Bgp = bsd + (long)n0*1024; ldb = 1024;
    nkt = 1024/64;
    if (tid < 128) rowmap[tid] = m0 + tid;
  }
  __syncthreads();
  const short *aS[4], *bS[4]; int cD[4];
  #pragma unroll
  for (int p = 0; p < 4; ++p){
    int c = p*256 + tid, row = c >> 3;
    int skb = ((c & 7) << 4) ^ ((row & 7) << 4);
    aS[p] = Ag + (long)rowmap[row]*lda + (skb >> 1);
    bS[p] = Bgp + (long)row*ldb + (skb >> 1);
    cD[p] = c*8;
  }
  auto ISSUE = [&](int kt_, int buf){
    int k0 = kt_*64;
    #pragma unroll
    for (int p = 0; p < 4; ++p){ GLL16(aS[p]+k0, &As[buf][cD[p]]); GLL16(bS[p]+k0, &Bs[buf][cD[p]]); }
  };
  f32x4 z = {0.f,0.f,0.f,0.f};
  f32x4 acc[4][4];
  for (int i=0;i<4;i++) for (int j=0;j<4;j++) acc[i][j]=z;
  ISSUE(0, 0);
  ISSUE(1, 1);
  wait_vm8();
  barrier_raw();
  int cur = 0;
  for (int kt = 0; kt < nkt; ++kt){
    #pragma unroll
    for (int ks = 0; ks < 2; ++ks){
      s16x8 af[4], bf[4];
      #pragma unroll
      for (int i = 0; i < 4; ++i){
        af[i] = frag_ld(&As[cur][0], wr*64 + i*16 + (lane&15), ks, lane);
        bf[i] = frag_ld(&Bs[cur][0], wc*64 + i*16 + (lane&15), ks, lane);
      }
      #pragma unroll
      for (int i = 0; i < 4; ++i)
        #pragma unroll
        for (int j = 0; j < 4; ++j)
          acc[i][j] = mfma16(af[i], bf[j], acc[i][j]);
    }
    barrier_raw();
    if (kt + 2 < nkt){
      ISSUE(kt + 2, cur);
      wait_vm8();
      barrier_raw();
    } else if (kt + 1 < nkt){
      wait_vm0();
      barrier_raw();
    }
    cur ^= 1;
  }
  if (expert){
    #pragma unroll
    for (int i = 0; i < 4; ++i){
      int mrow = wr*64 + i*16 + ((lane >> 4) << 2);
      #pragma unroll
      for (int r = 0; r < 4; ++r){
        int m = mrow + r;
        if (m0 + m < seg){
          int p = off + m0 + m;
          float w = permw[p];
          #pragma unroll
          for (int j = 0; j < 4; ++j){
            int col = n0 + wc*64 + j*16 + (lane & 15);
            y[(long)p*HDIM + col] = bf1(w*acc[i][j][r]);
          }
        }
      }
    }
  } else {
    #pragma unroll
    for (int i = 0; i < 4; ++i){
      int mrow = m0 + wr*64 + i*16 + ((lane >> 4) << 2);
      #pragma unroll
      for (int j = 0; j < 4; ++j){
        int col = n0 + wc*64 + j*16 + (lane & 15);
        #pragma unroll
        for (int r = 0; r < 4; ++r)
          out[(long)(mrow + r)*HDIM + col] = acc[i][j][r];
      }
    }
  }
}

// ---------------- finalize: out[t] += sum_k bf16 y[pairpos[t,k]] -----------
__global__ __launch_bounds__(256) void k_finalize(const short* __restrict__ y,
    const int* __restrict__ pairpos, float* __restrict__ out){
  int t = blockIdx.x, tid = threadIdx.x;
  const int* pp = pairpos + t*TOPK;
  float4* o4 = (float4*)(out + (long)t*HDIM);
  float4 acc = o4[tid];
  #pragma unroll
  for (int k = 0; k < TOPK; ++k){
    const short4 v = *(const short4*)(y + (long)pp[k]*HDIM + tid*4);
    acc.x += (float)__builtin_bit_cast(__bf16, v.x);
    acc.y += (float)__builtin_bit_cast(__bf16, v.y);
    acc.z += (float)__builtin_bit_cast(__bf16, v.z);
    acc.w += (float)__builtin_bit_cast(__bf16, v.w);
  }
  o4[tid] = acc;
}

extern "C" void kernel_launch(void* const* d_in, const int* in_sizes, int n_in,
                              void* d_out, int out_size, void* d_ws, size_t ws_size,
                              hipStream_t stream){
  const float* x    = (const float*)d_in[0];
  const float* rw   = (const float*)d_in[1];
  const float* bias = (const float*)d_in[2];
  const float* wgu  = (const float*)d_in[3];
  const float* wdn  = (const float*)d_in[4];
  const float* wsg  = (const float*)d_in[5];
  const float* wsu  = (const float*)d_in[6];
  const float* wsd  = (const float*)d_in[7];
  float* out = (float*)d_out;

  char* ws = (char*)d_ws;
  size_t o = 0;
  auto alloc = [&](size_t bytes){ void* p = ws + o; o += (bytes + 255) & ~(size_t)255; return p; };
  short* bgu  = (short*)alloc(67108864);   // [E,2I,H] bf16; dead after k_gu
  short* bdn  = (short*)alloc(33554432);   // [E,H,I]  bf16 (written inside k_gu tail blocks)
  short* bsg  = (short*)alloc(2097152);
  short* bsu  = (short*)alloc(2097152);
  short* bsd  = (short*)alloc(2097152);
  short* xb   = (short*)alloc(4194304);    // [T,H] bf16
  short* sb   = (short*)alloc(4194304);    // [T,IS] bf16
  short* hmid = (short*)alloc(12582912);   // [P,I] bf16
  int*   tki  = (int*)alloc(NPAIR*4);
  float* tkw  = (float*)alloc(NPAIR*4);
  int*   counts  = (int*)alloc(256);
  int*   offsets = (int*)alloc(256);
  int*   cursor  = (int*)alloc(256);
  int*   permt   = (int*)alloc(NPAIR*4);
  float* permw   = (float*)alloc(NPAIR*4);
  int*   pairpos = (int*)alloc(NPAIR*4);
  short* y = (short*)bgu;                  // alias: y [NPAIR,H] bf16 (25MB) over dead bgu
  (void)ws_size; (void)in_sizes; (void)n_in; (void)out_size;

  k_convert_router<<<dim3(512 + 2240), dim3(256), 0, stream>>>(
      wgu, wsg, wsu, wsd, bgu, bsg, bsu, bsd,
      x, rw, bias, xb, tki, tkw, counts);
  k_hist<<<dim3(NPAIR/1024), dim3(256), 0, stream>>>(tki, counts);
  k_scan<<<dim3(1), dim3(64), 0, stream>>>(counts, offsets, cursor);
  k_scatter<<<dim3(NPAIR/1024), dim3(256), 0, stream>>>(tki, tkw, cursor, permt, permw, pairpos);
  k_gu<<<dim3(8, 16, NEXP+10), dim3(256), 0, stream>>>(xb, bgu, bsg, bsu, offsets, permt,
                                                       hmid, sb, wdn, bdn);
  k_down<<<dim3(8, 16, NEXP+1), dim3(256), 0, stream>>>(hmid, bdn, sb, bsd, offsets, permt, permw, y, out);
  k_finalize<<<dim3(NTOK), dim3(256), 0, stream>>>(y, pairpos, out);
}